// Round 4
// baseline (169.400 us; speedup 1.0000x reference)
//
#include <hip/hip_runtime.h>
#include <hip/hip_bf16.h>

// MoLoRA = base linear + top-2 routed LoRA.
//   Abuf[T,2176] = [ bf16(x) | bf16(alpha*cw*(x@A_w^T)) ]
//   Bfull[O,2176] = [ bf16(W) | bf16(B2^T) ]   (B2[e*16+r,o]=B_w[e,o,r])
//   out[T,O] = Abuf @ Bfull^T     -- single bf16 MFMA GEMM, K=2176
// T=4096, H=2048, O=2048, E=8, R=16, Kaug=2176.
//
// R1: XOR k-chunk LDS swizzle -> SQ_LDS_BANK_CONFLICT 1.34e7 -> 0.
// R2: 128x64 tiles / fused router (3 dispatches).
// R3: 256x128 mega-block, 8 waves, 3-deep pipeline: 45.8us, Mfma 30%.
// R4: ks-split + fine 2-phase: 46.8us, flat -> schedule micro-structure not
//     the limiter at 1 block/CU.
// R5: 128x128, 2 blocks/CU co-resident + counted vmcnt: GEMM dropped below
//     the 41.8us harness fills (~38-40us, ~m97-plateau 900+ TF). Top-5 now
//     all fillBufferAligned => measured window includes ~85-100us of fixed
//     harness poison-fill; controllable budget is our ~55-60us of kernels.
// R6: collapse 3 dispatches -> 2. prep merged into router kernel:
//     - blocks 0..255: router (16 tokens each), launched FIRST (long pole);
//       phase 3 reads A_w directly as f32 + in-register RNE cvt (bitwise
//       identical to the old A2 path) -> no cross-block dependency, A2 dead.
//     - blocks 256..2303: W-row convert -> Bfull[:,0:2048].
//     - blocks 2304..2367: B_w pack -> Bfull[:,2048:2176].
//     Saves one launch gap + overlaps prep's 27MB under router's phases.

typedef __bf16 bf16x8 __attribute__((ext_vector_type(8)));
typedef float f32x4 __attribute__((ext_vector_type(4)));

__device__ __forceinline__ __bf16 f2bf(float f) { return (__bf16)f; }  // RNE (v_cvt_pk_bf16_f32)

__device__ __forceinline__ void ld_lds16(const void* g, void* l) {
  __builtin_amdgcn_global_load_lds((__attribute__((address_space(1))) void*)g,
                                   (__attribute__((address_space(3))) void*)l,
                                   16, 0, 0);
}

// ---------------- merged prep + router + LoRA-down ----------------
// grid 2368 x 256 threads. Static LDS ~66KB (router's xs) -> 2 blocks/CU max
// for every role; router blocks are the long pole and go first.
__global__ __launch_bounds__(256) void prep_router(
    const float* __restrict__ x, const float* __restrict__ gw,
    const float* __restrict__ Aw, const float* __restrict__ W,
    const float* __restrict__ Bw, __bf16* __restrict__ Abuf,
    __bf16* __restrict__ Bfull) {
  __shared__ __align__(16) __bf16 xs[16][2056];  // 64.25 KB, +8 pad
  __shared__ float red[4][16][8];
  __shared__ float cws[16][8];
  const int b = blockIdx.x;
  const int tid = threadIdx.x;

  if (b >= 256) {
    const int pb = b - 256;
    if (pb < 2048) {
      // ---- W row -> bf16 -> Bfull[pb, 0:2048] ----
      const float* src = W + (size_t)pb * 2048;
      __bf16* dst = Bfull + (size_t)pb * 2176;
      const int c = tid * 8;
      float4 a = *(const float4*)(src + c);
      float4 d = *(const float4*)(src + c + 4);
      bf16x8 v;
      v[0] = f2bf(a.x); v[1] = f2bf(a.y); v[2] = f2bf(a.z); v[3] = f2bf(a.w);
      v[4] = f2bf(d.x); v[5] = f2bf(d.y); v[6] = f2bf(d.z); v[7] = f2bf(d.w);
      *(bf16x8*)(dst + c) = v;
    } else {
      // ---- pack B_w [E,O,R] -> Bfull[o, 2048 + e*16 + r] ----
      const int idx = (pb - 2048) * 256 + tid;  // 0..16383
      const int e = idx >> 11, o = idx & 2047;
      const float4* s = (const float4*)(Bw + ((size_t)e * 2048 + o) * 16);
      float4 v0 = s[0], v1 = s[1], v2 = s[2], v3 = s[3];
      __bf16* d = Bfull + (size_t)o * 2176 + 2048 + e * 16;
      bf16x8 lo, hi;
      lo[0] = f2bf(v0.x); lo[1] = f2bf(v0.y); lo[2] = f2bf(v0.z); lo[3] = f2bf(v0.w);
      lo[4] = f2bf(v1.x); lo[5] = f2bf(v1.y); lo[6] = f2bf(v1.z); lo[7] = f2bf(v1.w);
      hi[0] = f2bf(v2.x); hi[1] = f2bf(v2.y); hi[2] = f2bf(v2.z); hi[3] = f2bf(v2.w);
      hi[4] = f2bf(v3.x); hi[5] = f2bf(v3.y); hi[6] = f2bf(v3.z); hi[7] = f2bf(v3.w);
      *(bf16x8*)d = lo;
      *(bf16x8*)(d + 8) = hi;
    }
    return;
  }

  // ================= router block: 16 tokens =================
  const int wave = tid >> 6, lane = tid & 63;
  const int t0 = b * 16;

  // ---- phase 1: x -> bf16 -> Abuf[:,0:2048] + LDS xs ----
#pragma unroll 4
  for (int i = 0; i < 16; ++i) {
    const float* xr = x + (size_t)(t0 + i) * 2048 + tid * 8;
    float4 a = *(const float4*)xr;
    float4 bb = *(const float4*)(xr + 4);
    bf16x8 v;
    v[0] = f2bf(a.x); v[1] = f2bf(a.y); v[2] = f2bf(a.z); v[3] = f2bf(a.w);
    v[4] = f2bf(bb.x); v[5] = f2bf(bb.y); v[6] = f2bf(bb.z); v[7] = f2bf(bb.w);
    *(bf16x8*)(Abuf + (size_t)(t0 + i) * 2176 + tid * 8) = v;
    *(bf16x8*)&xs[i][tid * 8] = v;
  }
  __syncthreads();

  // ---- phase 2: logits (token=tid&15, slice=tid>>4), reduce, top-2 ----
  const int tok = tid & 15, slc = tid >> 4;
  const int c0 = slc * 128;
  float acc[8] = {0, 0, 0, 0, 0, 0, 0, 0};
  for (int j8 = 0; j8 < 16; ++j8) {
    bf16x8 xv = *(const bf16x8*)&xs[tok][c0 + j8 * 8];
    float xf[8];
#pragma unroll
    for (int j = 0; j < 8; ++j) xf[j] = (float)xv[j];
#pragma unroll
    for (int e = 0; e < 8; ++e) {
      float4 g0 = *(const float4*)(gw + e * 2048 + c0 + j8 * 8);
      float4 g1 = *(const float4*)(gw + e * 2048 + c0 + j8 * 8 + 4);
      acc[e] += xf[0] * g0.x + xf[1] * g0.y + xf[2] * g0.z + xf[3] * g0.w +
                xf[4] * g1.x + xf[5] * g1.y + xf[6] * g1.z + xf[7] * g1.w;
    }
  }
#pragma unroll
  for (int e = 0; e < 8; ++e) {
    acc[e] += __shfl_down(acc[e], 16);
    acc[e] += __shfl_down(acc[e], 32);
  }
  if (lane < 16) {
#pragma unroll
    for (int e = 0; e < 8; ++e) red[wave][lane][e] = acc[e];
  }
  __syncthreads();
  if (tid < 16) {
    float lg[8];
#pragma unroll
    for (int e = 0; e < 8; ++e)
      lg[e] = red[0][tid][e] + red[1][tid][e] + red[2][tid][e] + red[3][tid][e];
    int a = 0;
    for (int e = 1; e < 8; ++e) if (lg[e] > lg[a]) a = e;
    int bb = (a == 0) ? 1 : 0;
    for (int e = 0; e < 8; ++e) if (e != a && lg[e] > lg[bb]) bb = e;
    const float d = __expf(lg[bb] - lg[a]);
    float o[8] = {0, 0, 0, 0, 0, 0, 0, 0};
    o[a] = 1.0f / (1.0f + d);
    o[bb] = d / (1.0f + d);
#pragma unroll
    for (int e = 0; e < 8; ++e) cws[tid][e] = o[e];
  }
  __syncthreads();

  // ---- phase 3: t = xs @ A_w^T, A_w loaded f32 + RNE cvt in-register ----
  const int m = lane & 15, q = lane >> 4;
  const int nt0 = wave * 2;
  f32x4 tacc[2] = {};
  for (int ks = 0; ks < 64; ++ks) {
    bf16x8 af = *(const bf16x8*)&xs[m][ks * 32 + q * 8];
#pragma unroll
    for (int h = 0; h < 2; ++h) {
      const float* ap = Aw + (size_t)((nt0 + h) * 16 + m) * 2048 + ks * 32 + q * 8;
      float4 a0 = *(const float4*)ap;
      float4 a1 = *(const float4*)(ap + 4);
      bf16x8 bfg;
      bfg[0] = f2bf(a0.x); bfg[1] = f2bf(a0.y); bfg[2] = f2bf(a0.z); bfg[3] = f2bf(a0.w);
      bfg[4] = f2bf(a1.x); bfg[5] = f2bf(a1.y); bfg[6] = f2bf(a1.z); bfg[7] = f2bf(a1.w);
      tacc[h] = __builtin_amdgcn_mfma_f32_16x16x32_bf16(af, bfg, tacc[h], 0, 0, 0);
    }
  }
  // ---- phase 4: scale + store. C layout: col=lane&15, row=q*4+reg ----
#pragma unroll
  for (int h = 0; h < 2; ++h) {
    const int nt = nt0 + h;
#pragma unroll
    for (int rg = 0; rg < 4; ++rg) {
      const int trow = q * 4 + rg;
      const float s = tacc[h][rg] * 16.0f * cws[trow][nt];
      Abuf[(size_t)(t0 + trow) * 2176 + 2048 + nt * 16 + m] = f2bf(s);
    }
  }
}

// ---------------- multi-block MFMA GEMM: C[m,n] = sum_k A[m,k]*B[n,k] ----------
// 128x128 tile, BK=64, 256 threads = 4 waves (2x2 of 64x64). LDS: 2 buffers x
// (A 16KB + B 16KB) = 64KB -> 2 blocks/CU co-resident (independent barrier
// groups; cross-block slip hides stage/barrier stalls). Grid 32x16 = 512 blocks
// = exactly 2/CU. Counted vmcnt(8): next tile's 8 gloads stay in flight across
// the barrier; this tile's 8 are guaranteed landed. XOR k-chunk swizzle as R1.
__global__ __launch_bounds__(256, 2) void mfma_gemm_bt4(
    const __bf16* __restrict__ A, const __bf16* __restrict__ B,
    float* __restrict__ C, int lda, int ldb, int ldc, int kiters) {
  __shared__ __align__(16) __bf16 lds[2 * 16384];  // 64 KB: [buf][A 8192 | B 8192]
  const int tid = threadIdx.x;
  const int wave = tid >> 6;
  const int lane = tid & 63;

  // XCD chunking: 512 wgs, 8 XCDs -> 64 consecutive ids per XCD, shaped 8Mx8N.
  const int wg = blockIdx.x + (blockIdx.y << 5);  // 32 M-tiles x 16 N-tiles
  const int xcd = wg & 7, loc = wg >> 3;          // loc 0..63
  const int tm = ((xcd & 3) * 8 + (loc >> 3)) * 128;
  const int tn = ((xcd >> 2) * 8 + (loc & 7)) * 128;

  const int srow = lane >> 3;                 // row within 8-row staging chunk
  const int skoff = ((lane & 7) ^ srow) * 8;  // XOR-swizzled k offset (elems)

  const int wr = wave >> 1, wc = wave & 1;    // 2x2 wave grid of 64x64 tiles
  const int rlo = lane & 7;
  const int rb3 = (lane >> 3) & 1;
  const int qb = lane >> 4;

  f32x4 acc[4][4] = {};

  // stage tile kt into buffer buf: 32 chunks ([8 rows][64 k] each), 8/wave
  auto stage = [&](int buf, int kt) {
    const int kc = kt * 64;
    __bf16* Ls = lds + buf * 16384;
#pragma unroll
    for (int r = 0; r < 4; ++r) {
      const int ch = wave + r * 4;  // A chunks 0..15 (rows tm..tm+127)
      ld_lds16(A + (size_t)(tm + ch * 8 + srow) * lda + kc + skoff, &Ls[ch * 512]);
    }
#pragma unroll
    for (int r = 0; r < 4; ++r) {
      const int ch = wave + r * 4;  // B chunks 0..15 (rows tn..tn+127)
      ld_lds16(B + (size_t)(tn + ch * 8 + srow) * ldb + kc + skoff,
               &Ls[8192 + ch * 512]);
    }
  };

  stage(0, 0);  // prologue: tile 0 in flight

  for (int kt = 0; kt < kiters; ++kt) {
    const int cb = kt & 1;
    if (kt + 1 < kiters) {
      stage(cb ^ 1, kt + 1);  // overwrites buffer read at kt-1 (barrier-safe)
      asm volatile("s_waitcnt vmcnt(8)" ::: "memory");  // tile kt landed
    } else {
      asm volatile("s_waitcnt vmcnt(0)" ::: "memory");
    }
    __builtin_amdgcn_s_barrier();

    const __bf16* As = lds + cb * 16384;
    const __bf16* Bs = As + 8192;
#pragma unroll
    for (int ks = 0; ks < 2; ++ks) {
      bf16x8 af[4], bfg[4];
      const int q8 = ((ks * 4 + qb) ^ rlo) * 8;
#pragma unroll
      for (int i = 0; i < 4; ++i) {
        const int rh = wr * 8 + i * 2 + rb3;
        af[i] = *(const bf16x8*)&As[rh * 512 + rlo * 64 + q8];
      }
#pragma unroll
      for (int j = 0; j < 4; ++j) {
        const int rh = wc * 8 + j * 2 + rb3;
        bfg[j] = *(const bf16x8*)&Bs[rh * 512 + rlo * 64 + q8];
      }
      __builtin_amdgcn_s_setprio(1);
#pragma unroll
      for (int i = 0; i < 4; ++i)
#pragma unroll
        for (int j = 0; j < 4; ++j)
          acc[i][j] =
              __builtin_amdgcn_mfma_f32_16x16x32_bf16(af[i], bfg[j], acc[i][j], 0, 0, 0);
      __builtin_amdgcn_s_setprio(0);
    }
    __builtin_amdgcn_s_barrier();  // all reads of buf cb done before next overwrite
  }

  // C/D layout: col = lane&15, row = (lane>>4)*4 + reg
  const int crow0 = tm + wr * 64 + (lane >> 4) * 4;
  const int ccol0 = tn + wc * 64 + (lane & 15);
#pragma unroll
  for (int i = 0; i < 4; ++i)
#pragma unroll
    for (int j = 0; j < 4; ++j)
#pragma unroll
      for (int rg = 0; rg < 4; ++rg)
        C[(size_t)(crow0 + i * 16 + rg) * ldc + ccol0 + j * 16] = acc[i][j][rg];
}

extern "C" void kernel_launch(void* const* d_in, const int* in_sizes, int n_in,
                              void* d_out, int out_size, void* d_ws, size_t ws_size,
                              hipStream_t stream) {
  const float* x = (const float*)d_in[0];       // [2,2048,2048] -> [4096,2048]
  const float* weight = (const float*)d_in[1];  // [2048,2048]
  const float* gate_w = (const float*)d_in[2];  // [8,2048]
  const float* A_w = (const float*)d_in[3];     // [8,16,2048] == [128,2048]
  const float* B_w = (const float*)d_in[4];     // [8,2048,16]
  float* out = (float*)d_out;                   // [4096,2048]

  char* ws = (char*)d_ws;
  __bf16* Abuf = (__bf16*)ws;                // [4096,2176] bf16 = 17,825,792 B
  __bf16* Bfull = (__bf16*)(ws + 17825792);  // [2048,2176] bf16 =  8,912,896 B

  // 1. merged prep + router: router blocks first (long pole), then W-convert
  //    and B_w-pack blocks fill remaining CUs.
  prep_router<<<2368, 256, 0, stream>>>(x, gate_w, A_w, weight, B_w, Abuf, Bfull);
  // 2. out = Abuf @ Bfull^T  (K=2176 fuses base + LoRA-up)
  mfma_gemm_bt4<<<dim3(32, 16), 256, 0, stream>>>(Abuf, Bfull, out, 2176, 2176,
                                                  2048, 34);
}